// Round 1
// baseline (15399.849 us; speedup 1.0000x reference)
//
#include <hip/hip_runtime.h>
#include <hip/hip_bf16.h>

// Problem constants (match reference setup_inputs)
#define Bb 64
#define Tt 256
#define Ee 300
#define Hh 512
#define NSTEP (2 * Tt - 1)  // 511
#define NNODE (Tt - 1)      // 255 internal nodes max per batch
#define N5H (5 * Hh)        // 2560

typedef __bf16 v8bf __attribute__((ext_vector_type(8)));
typedef float v4f __attribute__((ext_vector_type(4)));

__device__ __forceinline__ float sigm(float x) { return 1.f / (1.f + __expf(-x)); }

// ---------------------------------------------------------------------------
// Phase 1: leaf buffer projections.
//   c_buf = x @ W_x + b_x ; h_buf = sigmoid(x @ W_g + b_g) * tanh(c_buf)
// Block: 256 threads = 256 output cols; 16 bt-rows per block staged in LDS.
// fp32 VALU (exact); h stored bf16 (GEMM operand), c stored fp32 (epilogue).
// ---------------------------------------------------------------------------
__global__ __launch_bounds__(256) void leaf_kernel(
    const float* __restrict__ x, const float* __restrict__ Wx,
    const float* __restrict__ bx, const float* __restrict__ Wg,
    const float* __restrict__ bg,
    __hip_bfloat16* __restrict__ leaf_h, float* __restrict__ leaf_c)
{
    __shared__ __align__(16) float xs[16][304];  // 300 padded to 304 (float4 aligned)
    const int tid = threadIdx.x;
    const int n = blockIdx.x * 256 + tid;
    const long r0 = (long)blockIdx.y * 16;

    for (int i = tid; i < 16 * Ee; i += 256) {
        int r = i / Ee, k = i - r * Ee;
        xs[r][k] = x[(r0 + r) * Ee + k];
    }
    __syncthreads();

    float accx[16], accg[16];
    const float bxv = bx[n], bgv = bg[n];
#pragma unroll
    for (int r = 0; r < 16; r++) { accx[r] = bxv; accg[r] = bgv; }

    for (int k = 0; k < Ee; k += 4) {  // 300 % 4 == 0, no tail
        float wx[4], wg[4];
#pragma unroll
        for (int u = 0; u < 4; u++) {
            wx[u] = Wx[(long)(k + u) * Hh + n];
            wg[u] = Wg[(long)(k + u) * Hh + n];
        }
#pragma unroll
        for (int r = 0; r < 16; r++) {
            const float4 xv = *(const float4*)&xs[r][k];
            accx[r] = fmaf(xv.x, wx[0], accx[r]);
            accx[r] = fmaf(xv.y, wx[1], accx[r]);
            accx[r] = fmaf(xv.z, wx[2], accx[r]);
            accx[r] = fmaf(xv.w, wx[3], accx[r]);
            accg[r] = fmaf(xv.x, wg[0], accg[r]);
            accg[r] = fmaf(xv.y, wg[1], accg[r]);
            accg[r] = fmaf(xv.z, wg[2], accg[r]);
            accg[r] = fmaf(xv.w, wg[3], accg[r]);
        }
    }
#pragma unroll
    for (int r = 0; r < 16; r++) {
        const float c = accx[r];
        const float h = sigm(accg[r]) * tanhf(c);
        const long idx = (r0 + r) * Hh + n;
        leaf_c[idx] = c;
        leaf_h[idx] = __float2bfloat16(h);
    }
}

// ---------------------------------------------------------------------------
// Phase 2: schedule. One thread per batch simulates the shift-reduce stack
// (indices only) and assigns each internal node a topological level
// (1 + max(child levels)); then builds level-bucketed work lists.
// ---------------------------------------------------------------------------
__global__ __launch_bounds__(64) void sched_kernel(
    const int* __restrict__ trans,  // [NSTEP][Bb]
    int* __restrict__ node_l, int* __restrict__ node_r,  // [Bb][NNODE]
    int* __restrict__ root_src, int* __restrict__ offs,  // [Bb], [257]
    int* __restrict__ items, int* __restrict__ max_lv,   // [Bb*NNODE], [1]
    int* __restrict__ bar)
{
    __shared__ short stck[Bb][Tt];             // src: 0..Tt-1 leaf, Tt+nid internal
    __shared__ unsigned char lvl[Bb][NNODE];
    __shared__ unsigned char trans_s[NSTEP][Bb];
    __shared__ int counts[256];
    __shared__ int offs_s[257];
    __shared__ int maxl_s;
    const int b = threadIdx.x;

    if (b == 0) { maxl_s = 0; bar[0] = 0; }
    for (int i = b; i < 256; i += Bb) counts[i] = 0;
    // stage transitions to LDS with vector loads (NSTEP*Bb = 32704 ints, /4)
    for (int i4 = b; i4 < (NSTEP * Bb) / 4; i4 += Bb) {
        const int4 v = ((const int4*)trans)[i4];
        const int f = 4 * i4;
        trans_s[(f + 0) >> 6][(f + 0) & 63] = (unsigned char)v.x;
        trans_s[(f + 1) >> 6][(f + 1) & 63] = (unsigned char)v.y;
        trans_s[(f + 2) >> 6][(f + 2) & 63] = (unsigned char)v.z;
        trans_s[(f + 3) >> 6][(f + 3) & 63] = (unsigned char)v.w;
    }
    __syncthreads();

    int sp = 0, bp = Tt, nid = 0, maxl = 0;
    for (int t = 0; t < NSTEP; t++) {
        if (trans_s[t][b] == 0) {       // shift: push leaf (buffers popped from end)
            bp -= 1;
            stck[b][sp] = (short)bp; sp += 1;
        } else {                        // reduce
            const int rs = stck[b][sp - 1];
            const int ls = stck[b][sp - 2];
            const int l_lv = (ls < Tt) ? 0 : (int)lvl[b][ls - Tt];
            const int r_lv = (rs < Tt) ? 0 : (int)lvl[b][rs - Tt];
            const int le = 1 + (l_lv > r_lv ? l_lv : r_lv);
            lvl[b][nid] = (unsigned char)le;
            node_l[b * NNODE + nid] = ls;
            node_r[b * NNODE + nid] = rs;
            if (le > maxl) maxl = le;
            sp -= 2;
            stck[b][sp] = (short)(Tt + nid); sp += 1;
            nid += 1;
        }
    }
    root_src[b] = (int)stck[b][0];
    for (int i = 0; i < nid; i++) atomicAdd(&counts[lvl[b][i]], 1);
    atomicMax(&maxl_s, maxl);
    __syncthreads();
    if (b == 0) {
        int acc = 0;
        for (int l = 0; l < 256; l++) { offs_s[l] = acc; acc += counts[l]; }
        offs_s[256] = acc;
        max_lv[0] = maxl_s;
    }
    __syncthreads();
    for (int i = b; i < 256; i += Bb) counts[i] = offs_s[i];  // cursors
    __syncthreads();
    for (int i = 0; i < nid; i++) {
        const int pos = atomicAdd(&counts[lvl[b][i]], 1);
        items[pos] = (b << 16) | i;
    }
    for (int i = b; i < 257; i += Bb) offs[i] = offs_s[i];
}

// ---------------------------------------------------------------------------
// Phase 3: level-synchronous tree evaluation (persistent, cooperative grid).
// 256 blocks x 512 threads. Block g owns output columns j in {2g, 2g+1} with
// all 5 gates (W_r slice: 10 real cols padded to 16, bf16, transposed [n][k]
// in LDS, +8 pad per row to break bank conflicts). Per level: gather child h
// rows (bf16) straight from global into MFMA A-frags, 16x16x32 bf16 MFMA
// against LDS W, fp32 epilogue (sigmoid/tanh + child c from fp32 stores),
// write node h (bf16) + c (fp32); custom agent-scope counter barrier.
// ---------------------------------------------------------------------------
__global__ __launch_bounds__(512) void tree_kernel(
    const float* __restrict__ Wr, const float* __restrict__ br,
    const __hip_bfloat16* __restrict__ leaf_h, const float* __restrict__ leaf_c,
    __hip_bfloat16* __restrict__ node_h, float* __restrict__ node_c,
    const int* __restrict__ node_l, const int* __restrict__ node_r,
    const int* __restrict__ root_src, const int* __restrict__ offs,
    const int* __restrict__ items, const int* __restrict__ max_level,
    float* __restrict__ out, int* __restrict__ bar)
{
    __shared__ __align__(16) __bf16 Wt[16][1032];  // [local col][k], pad +8
    __shared__ float brs[16];
    __shared__ float Cs[64][17];                   // chunk outputs, pad 17
    __shared__ const __hip_bfloat16* hsrc_l[64];
    __shared__ const __hip_bfloat16* hsrc_r[64];
    __shared__ const float* csrc_l[64];
    __shared__ const float* csrc_r[64];
    __shared__ int outm[64];

    const int tid = threadIdx.x;
    const int g = blockIdx.x;  // column group: j = 2g, 2g+1

    // Load W_r slice as bf16, transposed. Local col c: gate=c%5, jj=c/5.
    for (int idx = tid; idx < 16 * 1024; idx += 512) {
        const int c = idx >> 10;
        const int k = idx & 1023;
        float v = 0.f;
        if (c < 10) {
            const int col = (c % 5) * Hh + 2 * g + (c / 5);
            v = Wr[(long)k * N5H + col];
        }
        Wt[c][k] = (__bf16)v;
    }
    if (tid < 16) {
        float v = 0.f;
        if (tid < 10) v = br[(tid % 5) * Hh + 2 * g + (tid / 5)];
        brs[tid] = v;
    }
    __syncthreads();

    const int ML = max_level[0];
    const int wave = tid >> 6;
    const int lane = tid & 63;
    const int mt = wave & 3;   // M-tile (16 rows each)
    const int kh = wave >> 2;  // K half (0: k<512, 1: k>=512)
    const int quad = lane >> 4;
    const int l15 = lane & 15;
    const int mrow = mt * 16 + l15;  // chunk row whose A this lane loads
    int epoch = 0;

    for (int lev = 1; lev <= ML; lev++) {
        const int s = offs[lev], e = offs[lev + 1];
        for (int base = s; base < e; base += 64) {
            const int M = (e - base < 64) ? (e - base) : 64;
            if (tid < 64) {
                const int m = tid;
                const int it = items[base + (m < M ? m : 0)];
                const int b = it >> 16;
                const int nd = it & 0xffff;
                const int ls = node_l[b * NNODE + nd];
                const int rs = node_r[b * NNODE + nd];
                hsrc_l[m] = (ls < Tt) ? (leaf_h + ((long)b * Tt + ls) * Hh)
                                      : (node_h + ((long)b * NNODE + (ls - Tt)) * Hh);
                hsrc_r[m] = (rs < Tt) ? (leaf_h + ((long)b * Tt + rs) * Hh)
                                      : (node_h + ((long)b * NNODE + (rs - Tt)) * Hh);
                csrc_l[m] = (ls < Tt) ? (leaf_c + ((long)b * Tt + ls) * Hh)
                                      : (node_c + ((long)b * NNODE + (ls - Tt)) * Hh);
                csrc_r[m] = (rs < Tt) ? (leaf_c + ((long)b * Tt + rs) * Hh)
                                      : (node_c + ((long)b * NNODE + (rs - Tt)) * Hh);
                int fl = it;
                if (Tt + nd == root_src[b]) fl |= (1 << 30);  // root marker
                if (m >= M) fl |= (1 << 29);                  // pad marker
                outm[m] = fl;
            }
            __syncthreads();

            // GEMM: A row = [h_l(512) | h_r(512)] gathered per lane from global.
            const __hip_bfloat16* lh = hsrc_l[mrow];
            const __hip_bfloat16* rh = hsrc_r[mrow];
            v4f acc = {0.f, 0.f, 0.f, 0.f};
            const int kbase = kh * 512;
#pragma unroll
            for (int kk = 0; kk < 512; kk += 32) {
                const int kl = kbase + kk + quad * 8;
                const __hip_bfloat16* ap = (kl < 512) ? (lh + kl) : (rh + (kl - 512));
                const v8bf a = *(const v8bf*)ap;
                const v8bf bf = *(const v8bf*)&Wt[l15][kl];
                acc = __builtin_amdgcn_mfma_f32_16x16x32_bf16(a, bf, acc, 0, 0, 0);
            }
            if (kh == 0) {
#pragma unroll
                for (int rg = 0; rg < 4; rg++) Cs[mt * 16 + quad * 4 + rg][l15] = acc[rg];
            }
            __syncthreads();
            if (kh == 1) {
#pragma unroll
                for (int rg = 0; rg < 4; rg++) Cs[mt * 16 + quad * 4 + rg][l15] += acc[rg];
            }
            __syncthreads();

            // Epilogue: 2 threads per work item (one per j column).
            if (tid < 128) {
                const int m = tid >> 1, jj = tid & 1;
                const int info = outm[m];
                if (!(info & (1 << 29))) {
                    const int b = (info >> 16) & 63;
                    const int nd = info & 0xffff;
                    const int j = 2 * g + jj;
                    const float iv = Cs[m][jj * 5 + 0] + brs[jj * 5 + 0];
                    const float fl = Cs[m][jj * 5 + 1] + brs[jj * 5 + 1];
                    const float fr = Cs[m][jj * 5 + 2] + brs[jj * 5 + 2];
                    const float gv = Cs[m][jj * 5 + 3] + brs[jj * 5 + 3];
                    const float ov = Cs[m][jj * 5 + 4] + brs[jj * 5 + 4];
                    const float cl = csrc_l[m][j];
                    const float cr = csrc_r[m][j];
                    const float c = sigm(iv) * tanhf(gv) + sigm(fl) * cl + sigm(fr) * cr;
                    const float h = sigm(ov) * tanhf(c);
                    const long ni = ((long)b * NNODE + nd) * Hh + j;
                    node_c[ni] = c;
                    node_h[ni] = __float2bfloat16(h);
                    if (info & (1 << 30)) out[(long)b * Hh + j] = h;
                }
            }
            __syncthreads();
        }
        // Grid barrier (agent scope). All blocks execute identical level/chunk
        // counts, so arrival counts match. bar zeroed by sched_kernel.
        epoch++;
        if (tid == 0) {
            __threadfence();  // release: drain node_h/node_c writes to device scope
            __hip_atomic_fetch_add(bar, 1, __ATOMIC_RELEASE, __HIP_MEMORY_SCOPE_AGENT);
            const int target = epoch * (int)gridDim.x;
            while (__hip_atomic_load(bar, __ATOMIC_ACQUIRE, __HIP_MEMORY_SCOPE_AGENT) < target) {
                __builtin_amdgcn_s_sleep(1);
            }
        }
        __syncthreads();
        __threadfence();  // acquire side for all threads
    }
}

// ---------------------------------------------------------------------------
extern "C" void kernel_launch(void* const* d_in, const int* in_sizes, int n_in,
                              void* d_out, int out_size, void* d_ws, size_t ws_size,
                              hipStream_t stream)
{
    const float* x   = (const float*)d_in[0];
    const int* trans = (const int*)d_in[1];
    const float* Wx  = (const float*)d_in[2];
    const float* bx  = (const float*)d_in[3];
    const float* Wg  = (const float*)d_in[4];
    const float* bg  = (const float*)d_in[5];
    const float* Wr  = (const float*)d_in[6];
    const float* br  = (const float*)d_in[7];
    float* out = (float*)d_out;

    char* p = (char*)d_ws;
    auto take = [&](size_t bytes) -> char* {
        char* r = p;
        p += (bytes + 255) & ~(size_t)255;
        return r;
    };
    __hip_bfloat16* leaf_h = (__hip_bfloat16*)take((size_t)Bb * Tt * Hh * 2);
    float* leaf_c          = (float*)take((size_t)Bb * Tt * Hh * 4);
    __hip_bfloat16* node_h = (__hip_bfloat16*)take((size_t)Bb * NNODE * Hh * 2);
    float* node_c          = (float*)take((size_t)Bb * NNODE * Hh * 4);
    int* node_l   = (int*)take((size_t)Bb * NNODE * 4);
    int* node_r   = (int*)take((size_t)Bb * NNODE * 4);
    int* root_src = (int*)take(Bb * 4);
    int* offs     = (int*)take(257 * 4);
    int* items    = (int*)take((size_t)Bb * NNODE * 4);
    int* max_lv   = (int*)take(4);
    int* bar      = (int*)take(4);
    // total ws use: ~101 MB

    hipLaunchKernelGGL(leaf_kernel, dim3(Hh / 256, (Bb * Tt) / 16), dim3(256), 0, stream,
                       x, Wx, bx, Wg, bg, leaf_h, leaf_c);
    hipLaunchKernelGGL(sched_kernel, dim3(1), dim3(64), 0, stream,
                       trans, node_l, node_r, root_src, offs, items, max_lv, bar);

    void* args[] = { (void*)&Wr, (void*)&br, (void*)&leaf_h, (void*)&leaf_c,
                     (void*)&node_h, (void*)&node_c, (void*)&node_l, (void*)&node_r,
                     (void*)&root_src, (void*)&offs, (void*)&items, (void*)&max_lv,
                     (void*)&out, (void*)&bar };
    hipLaunchCooperativeKernel((const void*)tree_kernel, dim3(256), dim3(512),
                               args, 0, stream);
}

// Round 2
// 5027.909 us; speedup vs baseline: 3.0629x; 3.0629x over previous
//
#include <hip/hip_runtime.h>
#include <hip/hip_bf16.h>

// Problem constants (match reference setup_inputs)
#define Bb 64
#define Tt 256
#define Ee 300
#define Hh 512
#define NSTEP (2 * Tt - 1)  // 511
#define NNODE (Tt - 1)      // 255 internal nodes max per batch
#define N5H (5 * Hh)        // 2560

typedef __bf16 v8bf __attribute__((ext_vector_type(8)));
typedef float v4f __attribute__((ext_vector_type(4)));
typedef unsigned long long u64;
typedef unsigned int u32;

__device__ __forceinline__ float sigm(float x) { return 1.f / (1.f + __expf(-x)); }

// ---------------------------------------------------------------------------
// Phase 1: leaf buffer projections.
//   c_buf = x @ W_x + b_x ; h_buf = sigmoid(x @ W_g + b_g) * tanh(c_buf)
// ---------------------------------------------------------------------------
__global__ __launch_bounds__(256) void leaf_kernel(
    const float* __restrict__ x, const float* __restrict__ Wx,
    const float* __restrict__ bx, const float* __restrict__ Wg,
    const float* __restrict__ bg,
    __hip_bfloat16* __restrict__ leaf_h, float* __restrict__ leaf_c)
{
    __shared__ __align__(16) float xs[16][304];
    const int tid = threadIdx.x;
    const int n = blockIdx.x * 256 + tid;
    const long r0 = (long)blockIdx.y * 16;

    for (int i = tid; i < 16 * Ee; i += 256) {
        int r = i / Ee, k = i - r * Ee;
        xs[r][k] = x[(r0 + r) * Ee + k];
    }
    __syncthreads();

    float accx[16], accg[16];
    const float bxv = bx[n], bgv = bg[n];
#pragma unroll
    for (int r = 0; r < 16; r++) { accx[r] = bxv; accg[r] = bgv; }

    for (int k = 0; k < Ee; k += 4) {
        float wx[4], wg[4];
#pragma unroll
        for (int u = 0; u < 4; u++) {
            wx[u] = Wx[(long)(k + u) * Hh + n];
            wg[u] = Wg[(long)(k + u) * Hh + n];
        }
#pragma unroll
        for (int r = 0; r < 16; r++) {
            const float4 xv = *(const float4*)&xs[r][k];
            accx[r] = fmaf(xv.x, wx[0], accx[r]);
            accx[r] = fmaf(xv.y, wx[1], accx[r]);
            accx[r] = fmaf(xv.z, wx[2], accx[r]);
            accx[r] = fmaf(xv.w, wx[3], accx[r]);
            accg[r] = fmaf(xv.x, wg[0], accg[r]);
            accg[r] = fmaf(xv.y, wg[1], accg[r]);
            accg[r] = fmaf(xv.z, wg[2], accg[r]);
            accg[r] = fmaf(xv.w, wg[3], accg[r]);
        }
    }
#pragma unroll
    for (int r = 0; r < 16; r++) {
        const float c = accx[r];
        const float h = sigm(accg[r]) * tanhf(c);
        const long idx = (r0 + r) * Hh + n;
        leaf_c[idx] = c;
        leaf_h[idx] = __float2bfloat16(h);
    }
}

// ---------------------------------------------------------------------------
// Phase 2: schedule (unchanged from R1 — works, ~negligible time).
// ---------------------------------------------------------------------------
__global__ __launch_bounds__(64) void sched_kernel(
    const int* __restrict__ trans,
    int* __restrict__ node_l, int* __restrict__ node_r,
    int* __restrict__ root_src, int* __restrict__ offs,
    int* __restrict__ items, int* __restrict__ max_lv,
    int* __restrict__ bar)
{
    __shared__ short stck[Bb][Tt];
    __shared__ unsigned char lvl[Bb][NNODE];
    __shared__ unsigned char trans_s[NSTEP][Bb];
    __shared__ int counts[256];
    __shared__ int offs_s[257];
    __shared__ int maxl_s;
    const int b = threadIdx.x;

    if (b == 0) { maxl_s = 0; bar[0] = 0; }
    for (int i = b; i < 256; i += Bb) counts[i] = 0;
    for (int i4 = b; i4 < (NSTEP * Bb) / 4; i4 += Bb) {
        const int4 v = ((const int4*)trans)[i4];
        const int f = 4 * i4;
        trans_s[(f + 0) >> 6][(f + 0) & 63] = (unsigned char)v.x;
        trans_s[(f + 1) >> 6][(f + 1) & 63] = (unsigned char)v.y;
        trans_s[(f + 2) >> 6][(f + 2) & 63] = (unsigned char)v.z;
        trans_s[(f + 3) >> 6][(f + 3) & 63] = (unsigned char)v.w;
    }
    __syncthreads();

    int sp = 0, bp = Tt, nid = 0, maxl = 0;
    for (int t = 0; t < NSTEP; t++) {
        if (trans_s[t][b] == 0) {
            bp -= 1;
            stck[b][sp] = (short)bp; sp += 1;
        } else {
            const int rs = stck[b][sp - 1];
            const int ls = stck[b][sp - 2];
            const int l_lv = (ls < Tt) ? 0 : (int)lvl[b][ls - Tt];
            const int r_lv = (rs < Tt) ? 0 : (int)lvl[b][rs - Tt];
            const int le = 1 + (l_lv > r_lv ? l_lv : r_lv);
            lvl[b][nid] = (unsigned char)le;
            node_l[b * NNODE + nid] = ls;
            node_r[b * NNODE + nid] = rs;
            if (le > maxl) maxl = le;
            sp -= 2;
            stck[b][sp] = (short)(Tt + nid); sp += 1;
            nid += 1;
        }
    }
    root_src[b] = (int)stck[b][0];
    for (int i = 0; i < nid; i++) atomicAdd(&counts[lvl[b][i]], 1);
    atomicMax(&maxl_s, maxl);
    __syncthreads();
    if (b == 0) {
        int acc = 0;
        for (int l = 0; l < 256; l++) { offs_s[l] = acc; acc += counts[l]; }
        offs_s[256] = acc;
        max_lv[0] = maxl_s;
    }
    __syncthreads();
    for (int i = b; i < 256; i += Bb) counts[i] = offs_s[i];
    __syncthreads();
    for (int i = 0; i < nid; i++) {
        const int pos = atomicAdd(&counts[lvl[b][i]], 1);
        items[pos] = (b << 16) | i;
    }
    for (int i = b; i < 257; i += Bb) offs[i] = offs_s[i];
}

// ---------------------------------------------------------------------------
// Phase 3: level-synchronous tree evaluation — FENCE-FREE cross-XCD protocol.
// All cross-block-mutable traffic (node_h, node_c, bar) goes through
// agent-scope RELAXED atomics => global_load/store with sc1 (L2 bypass,
// coherent at the shared Infinity Cache). No __threadfence() => no
// buffer_wbl2/buffer_inv L2 tag walks per level (R1's 59 us/level cost).
// Release ordering: all global stores in a chunk are issued by wave 0; tid 0
// (same wave) drains them with a wave-wide s_waitcnt(0) before the arrival
// atomicAdd. Read-only data (Wt, items, node_l/r, offs) keeps cached loads
// and now persists in L2 across levels.
// ---------------------------------------------------------------------------
__global__ __launch_bounds__(512) void tree_kernel(
    const float* __restrict__ Wr, const float* __restrict__ br,
    const __hip_bfloat16* __restrict__ leaf_h, const float* __restrict__ leaf_c,
    __hip_bfloat16* __restrict__ node_h, float* __restrict__ node_c,
    const int* __restrict__ node_l, const int* __restrict__ node_r,
    const int* __restrict__ root_src, const int* __restrict__ offs,
    const int* __restrict__ items, const int* __restrict__ max_level,
    float* __restrict__ out, int* __restrict__ bar)
{
    __shared__ __align__(16) __bf16 Wt[16][1032];  // [local col][k], pad +8
    __shared__ float brs[16];
    __shared__ float Cs[64][17];
    __shared__ const u64* hsrc_l[64];
    __shared__ const u64* hsrc_r[64];
    __shared__ int outm[64];

    const int tid = threadIdx.x;
    const int g = blockIdx.x;  // column group: j = 2g, 2g+1

    // Load W_r slice as bf16, transposed. Local col c: gate=c%5, jj=c/5.
    for (int idx = tid; idx < 16 * 1024; idx += 512) {
        const int c = idx >> 10;
        const int k = idx & 1023;
        float v = 0.f;
        if (c < 10) {
            const int col = (c % 5) * Hh + 2 * g + (c / 5);
            v = Wr[(long)k * N5H + col];
        }
        Wt[c][k] = (__bf16)v;
    }
    if (tid < 16) {
        float v = 0.f;
        if (tid < 10) v = br[(tid % 5) * Hh + 2 * g + (tid / 5)];
        brs[tid] = v;
    }
    __syncthreads();

    const int ML = max_level[0];
    const int wave = tid >> 6;
    const int lane = tid & 63;
    const int mt = wave & 3;   // M-tile (16 rows each)
    const int kh = wave >> 2;  // K half (0: k<512, 1: k>=512)
    const int quad = lane >> 4;
    const int l15 = lane & 15;
    const int mrow = mt * 16 + l15;
    int epoch = 0;

    const u64* leaf_h64 = (const u64*)leaf_h;   // 4 bf16 per u64
    const u64* node_h64 = (const u64*)node_h;
    u32* node_h32 = (u32*)node_h;               // 2 bf16 per u32

    for (int lev = 1; lev <= ML; lev++) {
        const int s = offs[lev], e = offs[lev + 1];
        for (int base = s; base < e; base += 64) {
            const int M = (e - base < 64) ? (e - base) : 64;
            float clv0 = 0.f, clv1 = 0.f, crv0 = 0.f, crv1 = 0.f;
            if (tid < 64) {
                const int m = tid;
                const int it = items[base + (m < M ? m : 0)];
                const int b = it >> 16;
                const int nd = it & 0xffff;
                const int ls = node_l[b * NNODE + nd];
                const int rs = node_r[b * NNODE + nd];
                hsrc_l[m] = (ls < Tt) ? leaf_h64 + ((long)b * Tt + ls) * (Hh / 4)
                                      : node_h64 + ((long)b * NNODE + (ls - Tt)) * (Hh / 4);
                hsrc_r[m] = (rs < Tt) ? leaf_h64 + ((long)b * Tt + rs) * (Hh / 4)
                                      : node_h64 + ((long)b * NNODE + (rs - Tt)) * (Hh / 4);
                const float* cl = (ls < Tt) ? leaf_c + ((long)b * Tt + ls) * Hh
                                            : node_c + ((long)b * NNODE + (ls - Tt)) * Hh;
                const float* cr = (rs < Tt) ? leaf_c + ((long)b * Tt + rs) * Hh
                                            : node_c + ((long)b * NNODE + (rs - Tt)) * Hh;
                const int j0 = 2 * g;
                // Prefetch child c now (overlaps the GEMM's latency).
                clv0 = __hip_atomic_load((float*)cl + j0,     __ATOMIC_RELAXED, __HIP_MEMORY_SCOPE_AGENT);
                clv1 = __hip_atomic_load((float*)cl + j0 + 1, __ATOMIC_RELAXED, __HIP_MEMORY_SCOPE_AGENT);
                crv0 = __hip_atomic_load((float*)cr + j0,     __ATOMIC_RELAXED, __HIP_MEMORY_SCOPE_AGENT);
                crv1 = __hip_atomic_load((float*)cr + j0 + 1, __ATOMIC_RELAXED, __HIP_MEMORY_SCOPE_AGENT);
                int fl = it;
                if (Tt + nd == root_src[b]) fl |= (1 << 30);  // root marker
                if (m >= M) fl |= (1 << 29);                  // pad marker
                outm[m] = fl;
            }
            __syncthreads();

            // GEMM: A row = [h_l(512) | h_r(512)], 2x8B agent loads per frag.
            const u64* lh = hsrc_l[mrow];
            const u64* rh = hsrc_r[mrow];
            const int kbase = kh * 512;
            v8bf a[16], w[16];
#pragma unroll
            for (int t = 0; t < 16; t++) {
                const int kl = kbase + t * 32 + quad * 8;
                const u64* ap = (kl < 512) ? (lh + (kl >> 2)) : (rh + ((kl - 512) >> 2));
                union { u64 u[2]; v8bf v; } av;
                av.u[0] = __hip_atomic_load((u64*)ap,     __ATOMIC_RELAXED, __HIP_MEMORY_SCOPE_AGENT);
                av.u[1] = __hip_atomic_load((u64*)ap + 1, __ATOMIC_RELAXED, __HIP_MEMORY_SCOPE_AGENT);
                a[t] = av.v;
                w[t] = *(const v8bf*)&Wt[l15][kl];
            }
            v4f acc = {0.f, 0.f, 0.f, 0.f};
#pragma unroll
            for (int t = 0; t < 16; t++)
                acc = __builtin_amdgcn_mfma_f32_16x16x32_bf16(a[t], w[t], acc, 0, 0, 0);

            if (kh == 0) {
#pragma unroll
                for (int rg = 0; rg < 4; rg++) Cs[mt * 16 + quad * 4 + rg][l15] = acc[rg];
            }
            __syncthreads();
            if (kh == 1) {
#pragma unroll
                for (int rg = 0; rg < 4; rg++) Cs[mt * 16 + quad * 4 + rg][l15] += acc[rg];
            }
            __syncthreads();

            // Epilogue: one thread per item, both j columns (wave 0 only —
            // keeps all global stores in wave 0 for the barrier's waitcnt).
            if (tid < 64) {
                const int m = tid;
                const int info = outm[m];
                if (!(info & (1 << 29))) {
                    const int b = (info >> 16) & 63;
                    const int nd = info & 0xffff;
                    float hv[2];
                    const float clv[2] = {clv0, clv1};
                    const float crv[2] = {crv0, crv1};
#pragma unroll
                    for (int jj = 0; jj < 2; jj++) {
                        const float iv = Cs[m][jj * 5 + 0] + brs[jj * 5 + 0];
                        const float fl = Cs[m][jj * 5 + 1] + brs[jj * 5 + 1];
                        const float fr = Cs[m][jj * 5 + 2] + brs[jj * 5 + 2];
                        const float gv = Cs[m][jj * 5 + 3] + brs[jj * 5 + 3];
                        const float ov = Cs[m][jj * 5 + 4] + brs[jj * 5 + 4];
                        const float c = sigm(iv) * tanhf(gv) + sigm(fl) * clv[jj] + sigm(fr) * crv[jj];
                        hv[jj] = sigm(ov) * tanhf(c);
                        __hip_atomic_store(node_c + ((long)b * NNODE + nd) * Hh + 2 * g + jj, c,
                                           __ATOMIC_RELAXED, __HIP_MEMORY_SCOPE_AGENT);
                    }
                    const __hip_bfloat16 hb0 = __float2bfloat16(hv[0]);
                    const __hip_bfloat16 hb1 = __float2bfloat16(hv[1]);
                    const u32 pack = (u32)(*(const unsigned short*)&hb0)
                                   | ((u32)(*(const unsigned short*)&hb1) << 16);
                    __hip_atomic_store(node_h32 + ((long)b * NNODE + nd) * (Hh / 2) + g, pack,
                                       __ATOMIC_RELAXED, __HIP_MEMORY_SCOPE_AGENT);
                    if (info & (1 << 30)) {
                        out[(long)b * Hh + 2 * g] = hv[0];
                        out[(long)b * Hh + 2 * g + 1] = hv[1];
                    }
                }
            }
            __syncthreads();  // protects Cs/outm/hsrc reuse in next chunk
        }
        if (lev < ML) {
            epoch++;
            if (tid == 0) {
                // Drain wave 0's sc1 stores to the coherence point (LLC),
                // then arrive. No cache-maintenance fences needed.
                __builtin_amdgcn_s_waitcnt(0);
                __hip_atomic_fetch_add(bar, 1, __ATOMIC_RELAXED, __HIP_MEMORY_SCOPE_AGENT);
                const int target = epoch * (int)gridDim.x;
                while (__hip_atomic_load(bar, __ATOMIC_RELAXED, __HIP_MEMORY_SCOPE_AGENT) < target) {
                    __builtin_amdgcn_s_sleep(2);
                }
            }
            __syncthreads();
        }
    }
}

// ---------------------------------------------------------------------------
extern "C" void kernel_launch(void* const* d_in, const int* in_sizes, int n_in,
                              void* d_out, int out_size, void* d_ws, size_t ws_size,
                              hipStream_t stream)
{
    const float* x   = (const float*)d_in[0];
    const int* trans = (const int*)d_in[1];
    const float* Wx  = (const float*)d_in[2];
    const float* bx  = (const float*)d_in[3];
    const float* Wg  = (const float*)d_in[4];
    const float* bg  = (const float*)d_in[5];
    const float* Wr  = (const float*)d_in[6];
    const float* br  = (const float*)d_in[7];
    float* out = (float*)d_out;

    char* p = (char*)d_ws;
    auto take = [&](size_t bytes) -> char* {
        char* r = p;
        p += (bytes + 255) & ~(size_t)255;
        return r;
    };
    __hip_bfloat16* leaf_h = (__hip_bfloat16*)take((size_t)Bb * Tt * Hh * 2);
    float* leaf_c          = (float*)take((size_t)Bb * Tt * Hh * 4);
    __hip_bfloat16* node_h = (__hip_bfloat16*)take((size_t)Bb * NNODE * Hh * 2);
    float* node_c          = (float*)take((size_t)Bb * NNODE * Hh * 4);
    int* node_l   = (int*)take((size_t)Bb * NNODE * 4);
    int* node_r   = (int*)take((size_t)Bb * NNODE * 4);
    int* root_src = (int*)take(Bb * 4);
    int* offs     = (int*)take(257 * 4);
    int* items    = (int*)take((size_t)Bb * NNODE * 4);
    int* max_lv   = (int*)take(4);
    int* bar      = (int*)take(4);

    hipLaunchKernelGGL(leaf_kernel, dim3(Hh / 256, (Bb * Tt) / 16), dim3(256), 0, stream,
                       x, Wx, bx, Wg, bg, leaf_h, leaf_c);
    hipLaunchKernelGGL(sched_kernel, dim3(1), dim3(64), 0, stream,
                       trans, node_l, node_r, root_src, offs, items, max_lv, bar);

    void* args[] = { (void*)&Wr, (void*)&br, (void*)&leaf_h, (void*)&leaf_c,
                     (void*)&node_h, (void*)&node_c, (void*)&node_l, (void*)&node_r,
                     (void*)&root_src, (void*)&offs, (void*)&items, (void*)&max_lv,
                     (void*)&out, (void*)&bar };
    hipLaunchCooperativeKernel((const void*)tree_kernel, dim3(256), dim3(512),
                               args, 0, stream);
}

// Round 3
// 3289.049 us; speedup vs baseline: 4.6822x; 1.5287x over previous
//
#include <hip/hip_runtime.h>
#include <hip/hip_bf16.h>

// Problem constants (match reference setup_inputs)
#define Bb 64
#define Tt 256
#define Ee 300
#define Hh 512
#define NSTEP (2 * Tt - 1)  // 511
#define NNODE (Tt - 1)      // 255 internal nodes max per batch
#define N5H (5 * Hh)        // 2560

typedef __bf16 v8bf __attribute__((ext_vector_type(8)));
typedef float v4f __attribute__((ext_vector_type(4)));
typedef unsigned long long u64;
typedef unsigned int u32;

__device__ __forceinline__ float sigm(float x) { return 1.f / (1.f + __expf(-x)); }

// ---------------------------------------------------------------------------
// Phase 1: leaf buffer projections.
//   c_buf = x @ W_x + b_x ; h_buf = sigmoid(x @ W_g + b_g) * tanh(c_buf)
// ---------------------------------------------------------------------------
__global__ __launch_bounds__(256) void leaf_kernel(
    const float* __restrict__ x, const float* __restrict__ Wx,
    const float* __restrict__ bx, const float* __restrict__ Wg,
    const float* __restrict__ bg,
    __hip_bfloat16* __restrict__ leaf_h, float* __restrict__ leaf_c)
{
    __shared__ __align__(16) float xs[16][304];
    const int tid = threadIdx.x;
    const int n = blockIdx.x * 256 + tid;
    const long r0 = (long)blockIdx.y * 16;

    for (int i = tid; i < 16 * Ee; i += 256) {
        int r = i / Ee, k = i - r * Ee;
        xs[r][k] = x[(r0 + r) * Ee + k];
    }
    __syncthreads();

    float accx[16], accg[16];
    const float bxv = bx[n], bgv = bg[n];
#pragma unroll
    for (int r = 0; r < 16; r++) { accx[r] = bxv; accg[r] = bgv; }

    for (int k = 0; k < Ee; k += 4) {
        float wx[4], wg[4];
#pragma unroll
        for (int u = 0; u < 4; u++) {
            wx[u] = Wx[(long)(k + u) * Hh + n];
            wg[u] = Wg[(long)(k + u) * Hh + n];
        }
#pragma unroll
        for (int r = 0; r < 16; r++) {
            const float4 xv = *(const float4*)&xs[r][k];
            accx[r] = fmaf(xv.x, wx[0], accx[r]);
            accx[r] = fmaf(xv.y, wx[1], accx[r]);
            accx[r] = fmaf(xv.z, wx[2], accx[r]);
            accx[r] = fmaf(xv.w, wx[3], accx[r]);
            accg[r] = fmaf(xv.x, wg[0], accg[r]);
            accg[r] = fmaf(xv.y, wg[1], accg[r]);
            accg[r] = fmaf(xv.z, wg[2], accg[r]);
            accg[r] = fmaf(xv.w, wg[3], accg[r]);
        }
    }
#pragma unroll
    for (int r = 0; r < 16; r++) {
        const float c = accx[r];
        const float h = sigm(accg[r]) * tanhf(c);
        const long idx = (r0 + r) * Hh + n;
        leaf_c[idx] = c;
        leaf_h[idx] = __float2bfloat16(h);
    }
}

// ---------------------------------------------------------------------------
// Phase 2: schedule (unchanged logic; now zeroes the 256 barrier slots).
// ---------------------------------------------------------------------------
__global__ __launch_bounds__(64) void sched_kernel(
    const int* __restrict__ trans,
    int* __restrict__ node_l, int* __restrict__ node_r,
    int* __restrict__ root_src, int* __restrict__ offs,
    int* __restrict__ items, int* __restrict__ max_lv,
    int* __restrict__ slots)
{
    __shared__ short stck[Bb][Tt];
    __shared__ unsigned char lvl[Bb][NNODE];
    __shared__ unsigned char trans_s[NSTEP][Bb];
    __shared__ int counts[256];
    __shared__ int offs_s[257];
    __shared__ int maxl_s;
    const int b = threadIdx.x;

    if (b == 0) maxl_s = 0;
    for (int i = b; i < 256; i += Bb) { counts[i] = 0; slots[i] = 0; }
    for (int i4 = b; i4 < (NSTEP * Bb) / 4; i4 += Bb) {
        const int4 v = ((const int4*)trans)[i4];
        const int f = 4 * i4;
        trans_s[(f + 0) >> 6][(f + 0) & 63] = (unsigned char)v.x;
        trans_s[(f + 1) >> 6][(f + 1) & 63] = (unsigned char)v.y;
        trans_s[(f + 2) >> 6][(f + 2) & 63] = (unsigned char)v.z;
        trans_s[(f + 3) >> 6][(f + 3) & 63] = (unsigned char)v.w;
    }
    __syncthreads();

    int sp = 0, bp = Tt, nid = 0, maxl = 0;
    for (int t = 0; t < NSTEP; t++) {
        if (trans_s[t][b] == 0) {
            bp -= 1;
            stck[b][sp] = (short)bp; sp += 1;
        } else {
            const int rs = stck[b][sp - 1];
            const int ls = stck[b][sp - 2];
            const int l_lv = (ls < Tt) ? 0 : (int)lvl[b][ls - Tt];
            const int r_lv = (rs < Tt) ? 0 : (int)lvl[b][rs - Tt];
            const int le = 1 + (l_lv > r_lv ? l_lv : r_lv);
            lvl[b][nid] = (unsigned char)le;
            node_l[b * NNODE + nid] = ls;
            node_r[b * NNODE + nid] = rs;
            if (le > maxl) maxl = le;
            sp -= 2;
            stck[b][sp] = (short)(Tt + nid); sp += 1;
            nid += 1;
        }
    }
    root_src[b] = (int)stck[b][0];
    for (int i = 0; i < nid; i++) atomicAdd(&counts[lvl[b][i]], 1);
    atomicMax(&maxl_s, maxl);
    __syncthreads();
    if (b == 0) {
        int acc = 0;
        for (int l = 0; l < 256; l++) { offs_s[l] = acc; acc += counts[l]; }
        offs_s[256] = acc;
        max_lv[0] = maxl_s;
    }
    __syncthreads();
    for (int i = b; i < 256; i += Bb) counts[i] = offs_s[i];
    __syncthreads();
    for (int i = 0; i < nid; i++) {
        const int pos = atomicAdd(&counts[lvl[b][i]], 1);
        items[pos] = (b << 16) | i;
    }
    for (int i = b; i < 257; i += Bb) offs[i] = offs_s[i];
}

// ---------------------------------------------------------------------------
// Phase 3: level-synchronous tree evaluation. Fence-free cross-XCD protocol
// (R2) + zero-RMW slot barrier (R3): arrival = one relaxed agent store to
// slots[blockIdx.x]; wait = wave 0 polls all 256 slots (4 loads/lane) with
// __all reduction. No atomicAdd serialization. Metadata for the level is
// prefetched BEFORE the wait; leaf child data uses cached loads (immutable),
// node child data uses agent-scope (LLC-coherent) loads.
// ---------------------------------------------------------------------------
__global__ __launch_bounds__(512) void tree_kernel(
    const float* __restrict__ Wr, const float* __restrict__ br,
    const __hip_bfloat16* __restrict__ leaf_h, const float* __restrict__ leaf_c,
    __hip_bfloat16* __restrict__ node_h, float* __restrict__ node_c,
    const int* __restrict__ node_l, const int* __restrict__ node_r,
    const int* __restrict__ root_src, const int* __restrict__ offs,
    const int* __restrict__ items, const int* __restrict__ max_level,
    float* __restrict__ out, int* __restrict__ slots)
{
    __shared__ __align__(16) __bf16 Wt[16][1032];  // [local col][k], pad +8
    __shared__ float brs[16];
    __shared__ float Cs0[64][17];   // kh=0 partial
    __shared__ float Cs1[64][17];   // kh=1 partial
    __shared__ u64 hsl[64], hsr[64];  // tagged h pointers (bit0 = leaf)
    __shared__ u64 csl[64], csr[64];  // tagged c pointers
    __shared__ int outm[64];

    const int tid = threadIdx.x;
    const int g = blockIdx.x;  // column group: j = 2g, 2g+1

    // Load W_r slice as bf16, transposed. Local col c: gate=c%5, jj=c/5.
    for (int idx = tid; idx < 16 * 1024; idx += 512) {
        const int c = idx >> 10;
        const int k = idx & 1023;
        float v = 0.f;
        if (c < 10) {
            const int col = (c % 5) * Hh + 2 * g + (c / 5);
            v = Wr[(long)k * N5H + col];
        }
        Wt[c][k] = (__bf16)v;
    }
    if (tid < 16) {
        float v = 0.f;
        if (tid < 10) v = br[(tid % 5) * Hh + 2 * g + (tid / 5)];
        brs[tid] = v;
    }
    __syncthreads();

    const int ML = max_level[0];
    const int wave = tid >> 6;
    const int lane = tid & 63;
    const int mt = wave & 3;   // M-tile (16 rows each)
    const int kh = wave >> 2;  // K half (0: left child k<512, 1: right child)
    const int quad = lane >> 4;
    const int l15 = lane & 15;
    const int mrow = mt * 16 + l15;

    const u64* leaf_h64 = (const u64*)leaf_h;   // 4 bf16 per u64
    const u64* node_h64 = (const u64*)node_h;
    u32* node_h32 = (u32*)node_h;               // 2 bf16 per u32

    // Build the per-chunk pointer/flag tables (barrier-independent metadata).
    auto prep = [&](int base, int M) {
        if (tid < 64) {
            const int m = tid;
            const int it = items[base + (m < M ? m : 0)];
            const int b = it >> 16;
            const int nd = it & 0xffff;
            const int ls = node_l[b * NNODE + nd];
            const int rs = node_r[b * NNODE + nd];
            u64 hl, cl, hr, cr;
            if (ls < Tt) {
                hl = (u64)(leaf_h64 + ((long)b * Tt + ls) * (Hh / 4)) | 1ull;
                cl = (u64)(leaf_c   + ((long)b * Tt + ls) * Hh) | 1ull;
            } else {
                hl = (u64)(node_h64 + ((long)b * NNODE + (ls - Tt)) * (Hh / 4));
                cl = (u64)(node_c   + ((long)b * NNODE + (ls - Tt)) * Hh);
            }
            if (rs < Tt) {
                hr = (u64)(leaf_h64 + ((long)b * Tt + rs) * (Hh / 4)) | 1ull;
                cr = (u64)(leaf_c   + ((long)b * Tt + rs) * Hh) | 1ull;
            } else {
                hr = (u64)(node_h64 + ((long)b * NNODE + (rs - Tt)) * (Hh / 4));
                cr = (u64)(node_c   + ((long)b * NNODE + (rs - Tt)) * Hh);
            }
            hsl[m] = hl; hsr[m] = hr; csl[m] = cl; csr[m] = cr;
            int fl = it;
            if (Tt + nd == root_src[b]) fl |= (1 << 30);  // root marker
            if (m >= M) fl |= (1 << 29);                  // pad marker
            outm[m] = fl;
        }
    };

    for (int lev = 1; lev <= ML; lev++) {
        const int s = offs[lev], e = offs[lev + 1];
        {
            const int M0 = (e - s < 64) ? (e - s) : 64;
            prep(s, M0);  // metadata loads overlap the barrier wait below
        }
        if (lev > 1 && wave == 0) {
            // Wait for all 256 blocks to finish level lev-1: poll slot array.
            const int need = lev - 1;
            const int* sl = slots + 4 * lane;
            for (;;) {
                const int a0 = __hip_atomic_load(sl + 0, __ATOMIC_RELAXED, __HIP_MEMORY_SCOPE_AGENT);
                const int a1 = __hip_atomic_load(sl + 1, __ATOMIC_RELAXED, __HIP_MEMORY_SCOPE_AGENT);
                const int a2 = __hip_atomic_load(sl + 2, __ATOMIC_RELAXED, __HIP_MEMORY_SCOPE_AGENT);
                const int a3 = __hip_atomic_load(sl + 3, __ATOMIC_RELAXED, __HIP_MEMORY_SCOPE_AGENT);
                const bool ok = (a0 >= need) & (a1 >= need) & (a2 >= need) & (a3 >= need);
                if (__all(ok)) break;
            }
        }
        __syncthreads();

        for (int base = s; base < e; base += 64) {
            const int M = (e - base < 64) ? (e - base) : 64;
            if (base != s) { prep(base, M); __syncthreads(); }

            // Child-c prefetch (overlaps the GEMM latency below).
            float clv0 = 0.f, clv1 = 0.f, crv0 = 0.f, crv1 = 0.f;
            if (tid < 64) {
                const u64 cl = csl[tid], cr = csr[tid];
                const float* clp = (const float*)(cl & ~1ull) + 2 * g;
                const float* crp = (const float*)(cr & ~1ull) + 2 * g;
                if (cl & 1) { clv0 = clp[0]; clv1 = clp[1]; }
                else {
                    clv0 = __hip_atomic_load(clp,     __ATOMIC_RELAXED, __HIP_MEMORY_SCOPE_AGENT);
                    clv1 = __hip_atomic_load(clp + 1, __ATOMIC_RELAXED, __HIP_MEMORY_SCOPE_AGENT);
                }
                if (cr & 1) { crv0 = crp[0]; crv1 = crp[1]; }
                else {
                    crv0 = __hip_atomic_load(crp,     __ATOMIC_RELAXED, __HIP_MEMORY_SCOPE_AGENT);
                    crv1 = __hip_atomic_load(crp + 1, __ATOMIC_RELAXED, __HIP_MEMORY_SCOPE_AGENT);
                }
            }

            // A gather: this wave's child row (kh picks left/right child).
            const u64 pt = kh ? hsr[mrow] : hsl[mrow];
            const u64* hp = (const u64*)(pt & ~1ull);
            v8bf a[16];
            if (pt & 1) {  // leaf child: immutable -> cached loads (L2 reuse)
#pragma unroll
                for (int t = 0; t < 16; t++)
                    a[t] = *(const v8bf*)(hp + ((t * 32 + quad * 8) >> 2));
            } else {       // node child: LLC-coherent agent loads
#pragma unroll
                for (int t = 0; t < 16; t++) {
                    union { u64 u[2]; v8bf v; } av;
                    const u64* ap = hp + ((t * 32 + quad * 8) >> 2);
                    av.u[0] = __hip_atomic_load((u64*)ap,     __ATOMIC_RELAXED, __HIP_MEMORY_SCOPE_AGENT);
                    av.u[1] = __hip_atomic_load((u64*)ap + 1, __ATOMIC_RELAXED, __HIP_MEMORY_SCOPE_AGENT);
                    a[t] = av.v;
                }
            }
            v4f acc = {0.f, 0.f, 0.f, 0.f};
#pragma unroll
            for (int t = 0; t < 16; t++) {
                const v8bf wv = *(const v8bf*)&Wt[l15][kh * 512 + t * 32 + quad * 8];
                acc = __builtin_amdgcn_mfma_f32_16x16x32_bf16(a[t], wv, acc, 0, 0, 0);
            }
            {
                float (*Cp)[17] = kh ? Cs1 : Cs0;
#pragma unroll
                for (int rg = 0; rg < 4; rg++) Cp[mt * 16 + quad * 4 + rg][l15] = acc[rg];
            }
            __syncthreads();

            // Epilogue: wave 0 only (keeps all mutable stores in wave 0 so
            // tid 0's s_waitcnt(0) drains them before the slot store).
            if (tid < 64) {
                const int m = tid;
                const int info = outm[m];
                if (!(info & (1 << 29))) {
                    const int b = (info >> 16) & 63;
                    const int nd = info & 0xffff;
                    float hv[2];
                    const float clv[2] = {clv0, clv1};
                    const float crv[2] = {crv0, crv1};
#pragma unroll
                    for (int jj = 0; jj < 2; jj++) {
                        const float iv = Cs0[m][jj * 5 + 0] + Cs1[m][jj * 5 + 0] + brs[jj * 5 + 0];
                        const float fl = Cs0[m][jj * 5 + 1] + Cs1[m][jj * 5 + 1] + brs[jj * 5 + 1];
                        const float fr = Cs0[m][jj * 5 + 2] + Cs1[m][jj * 5 + 2] + brs[jj * 5 + 2];
                        const float gv = Cs0[m][jj * 5 + 3] + Cs1[m][jj * 5 + 3] + brs[jj * 5 + 3];
                        const float ov = Cs0[m][jj * 5 + 4] + Cs1[m][jj * 5 + 4] + brs[jj * 5 + 4];
                        const float c = sigm(iv) * tanhf(gv) + sigm(fl) * clv[jj] + sigm(fr) * crv[jj];
                        hv[jj] = sigm(ov) * tanhf(c);
                        __hip_atomic_store(node_c + ((long)b * NNODE + nd) * Hh + 2 * g + jj, c,
                                           __ATOMIC_RELAXED, __HIP_MEMORY_SCOPE_AGENT);
                    }
                    const __hip_bfloat16 hb0 = __float2bfloat16(hv[0]);
                    const __hip_bfloat16 hb1 = __float2bfloat16(hv[1]);
                    const u32 pack = (u32)(*(const unsigned short*)&hb0)
                                   | ((u32)(*(const unsigned short*)&hb1) << 16);
                    __hip_atomic_store(node_h32 + ((long)b * NNODE + nd) * (Hh / 2) + g, pack,
                                       __ATOMIC_RELAXED, __HIP_MEMORY_SCOPE_AGENT);
                    if (info & (1 << 30)) {
                        out[(long)b * Hh + 2 * g] = hv[0];
                        out[(long)b * Hh + 2 * g + 1] = hv[1];
                    }
                }
            }
        }

        // Arrive: drain wave 0's stores to the coherence point, then one
        // plain agent store — no RMW, no same-line serialization.
        if (lev < ML && tid == 0) {
            __builtin_amdgcn_s_waitcnt(0);
            __hip_atomic_store(&slots[blockIdx.x], lev, __ATOMIC_RELAXED, __HIP_MEMORY_SCOPE_AGENT);
        }
    }
}

// ---------------------------------------------------------------------------
extern "C" void kernel_launch(void* const* d_in, const int* in_sizes, int n_in,
                              void* d_out, int out_size, void* d_ws, size_t ws_size,
                              hipStream_t stream)
{
    const float* x   = (const float*)d_in[0];
    const int* trans = (const int*)d_in[1];
    const float* Wx  = (const float*)d_in[2];
    const float* bx  = (const float*)d_in[3];
    const float* Wg  = (const float*)d_in[4];
    const float* bg  = (const float*)d_in[5];
    const float* Wr  = (const float*)d_in[6];
    const float* br  = (const float*)d_in[7];
    float* out = (float*)d_out;

    char* p = (char*)d_ws;
    auto take = [&](size_t bytes) -> char* {
        char* r = p;
        p += (bytes + 255) & ~(size_t)255;
        return r;
    };
    __hip_bfloat16* leaf_h = (__hip_bfloat16*)take((size_t)Bb * Tt * Hh * 2);
    float* leaf_c          = (float*)take((size_t)Bb * Tt * Hh * 4);
    __hip_bfloat16* node_h = (__hip_bfloat16*)take((size_t)Bb * NNODE * Hh * 2);
    float* node_c          = (float*)take((size_t)Bb * NNODE * Hh * 4);
    int* node_l   = (int*)take((size_t)Bb * NNODE * 4);
    int* node_r   = (int*)take((size_t)Bb * NNODE * 4);
    int* root_src = (int*)take(Bb * 4);
    int* offs     = (int*)take(257 * 4);
    int* items    = (int*)take((size_t)Bb * NNODE * 4);
    int* max_lv   = (int*)take(4);
    int* slots    = (int*)take(256 * 4);

    hipLaunchKernelGGL(leaf_kernel, dim3(Hh / 256, (Bb * Tt) / 16), dim3(256), 0, stream,
                       x, Wx, bx, Wg, bg, leaf_h, leaf_c);
    hipLaunchKernelGGL(sched_kernel, dim3(1), dim3(64), 0, stream,
                       trans, node_l, node_r, root_src, offs, items, max_lv, slots);

    void* args[] = { (void*)&Wr, (void*)&br, (void*)&leaf_h, (void*)&leaf_c,
                     (void*)&node_h, (void*)&node_c, (void*)&node_l, (void*)&node_r,
                     (void*)&root_src, (void*)&offs, (void*)&items, (void*)&max_lv,
                     (void*)&out, (void*)&slots };
    hipLaunchCooperativeKernel((const void*)tree_kernel, dim3(256), dim3(512),
                               args, 0, stream);
}

// Round 4
// 2780.664 us; speedup vs baseline: 5.5382x; 1.1828x over previous
//
#include <hip/hip_runtime.h>
#include <hip/hip_bf16.h>

// Problem constants (match reference setup_inputs)
#define Bb 64
#define Tt 256
#define Ee 300
#define Hh 512
#define NSTEP (2 * Tt - 1)  // 511
#define NNODE (Tt - 1)      // 255 internal nodes max per batch
#define N5H (5 * Hh)        // 2560

typedef __bf16 v8bf __attribute__((ext_vector_type(8)));
typedef float v4f __attribute__((ext_vector_type(4)));
typedef unsigned long long u64;
typedef unsigned int u32;

__device__ __forceinline__ float sigm(float x) { return 1.f / (1.f + __expf(-x)); }

// ---------------------------------------------------------------------------
// Phase 1: leaf buffer projections.
//   c_buf = x @ W_x + b_x ; h_buf = sigmoid(x @ W_g + b_g) * tanh(c_buf)
// ---------------------------------------------------------------------------
__global__ __launch_bounds__(256) void leaf_kernel(
    const float* __restrict__ x, const float* __restrict__ Wx,
    const float* __restrict__ bx, const float* __restrict__ Wg,
    const float* __restrict__ bg,
    __hip_bfloat16* __restrict__ leaf_h, float* __restrict__ leaf_c)
{
    __shared__ __align__(16) float xs[16][304];
    const int tid = threadIdx.x;
    const int n = blockIdx.x * 256 + tid;
    const long r0 = (long)blockIdx.y * 16;

    for (int i = tid; i < 16 * Ee; i += 256) {
        int r = i / Ee, k = i - r * Ee;
        xs[r][k] = x[(r0 + r) * Ee + k];
    }
    __syncthreads();

    float accx[16], accg[16];
    const float bxv = bx[n], bgv = bg[n];
#pragma unroll
    for (int r = 0; r < 16; r++) { accx[r] = bxv; accg[r] = bgv; }

    for (int k = 0; k < Ee; k += 4) {
        float wx[4], wg[4];
#pragma unroll
        for (int u = 0; u < 4; u++) {
            wx[u] = Wx[(long)(k + u) * Hh + n];
            wg[u] = Wg[(long)(k + u) * Hh + n];
        }
#pragma unroll
        for (int r = 0; r < 16; r++) {
            const float4 xv = *(const float4*)&xs[r][k];
            accx[r] = fmaf(xv.x, wx[0], accx[r]);
            accx[r] = fmaf(xv.y, wx[1], accx[r]);
            accx[r] = fmaf(xv.z, wx[2], accx[r]);
            accx[r] = fmaf(xv.w, wx[3], accx[r]);
            accg[r] = fmaf(xv.x, wg[0], accg[r]);
            accg[r] = fmaf(xv.y, wg[1], accg[r]);
            accg[r] = fmaf(xv.z, wg[2], accg[r]);
            accg[r] = fmaf(xv.w, wg[3], accg[r]);
        }
    }
#pragma unroll
    for (int r = 0; r < 16; r++) {
        const float c = accx[r];
        const float h = sigm(accg[r]) * tanhf(c);
        const long idx = (r0 + r) * Hh + n;
        leaf_c[idx] = c;
        leaf_h[idx] = __float2bfloat16(h);
    }
}

// ---------------------------------------------------------------------------
// Phase 2: schedule (unchanged; zeroes the 256 barrier slots).
// ---------------------------------------------------------------------------
__global__ __launch_bounds__(64) void sched_kernel(
    const int* __restrict__ trans,
    int* __restrict__ node_l, int* __restrict__ node_r,
    int* __restrict__ root_src, int* __restrict__ offs,
    int* __restrict__ items, int* __restrict__ max_lv,
    int* __restrict__ slots)
{
    __shared__ short stck[Bb][Tt];
    __shared__ unsigned char lvl[Bb][NNODE];
    __shared__ unsigned char trans_s[NSTEP][Bb];
    __shared__ int counts[256];
    __shared__ int offs_s[257];
    __shared__ int maxl_s;
    const int b = threadIdx.x;

    if (b == 0) maxl_s = 0;
    for (int i = b; i < 256; i += Bb) { counts[i] = 0; slots[i] = 0; }
    for (int i4 = b; i4 < (NSTEP * Bb) / 4; i4 += Bb) {
        const int4 v = ((const int4*)trans)[i4];
        const int f = 4 * i4;
        trans_s[(f + 0) >> 6][(f + 0) & 63] = (unsigned char)v.x;
        trans_s[(f + 1) >> 6][(f + 1) & 63] = (unsigned char)v.y;
        trans_s[(f + 2) >> 6][(f + 2) & 63] = (unsigned char)v.z;
        trans_s[(f + 3) >> 6][(f + 3) & 63] = (unsigned char)v.w;
    }
    __syncthreads();

    int sp = 0, bp = Tt, nid = 0, maxl = 0;
    for (int t = 0; t < NSTEP; t++) {
        if (trans_s[t][b] == 0) {
            bp -= 1;
            stck[b][sp] = (short)bp; sp += 1;
        } else {
            const int rs = stck[b][sp - 1];
            const int ls = stck[b][sp - 2];
            const int l_lv = (ls < Tt) ? 0 : (int)lvl[b][ls - Tt];
            const int r_lv = (rs < Tt) ? 0 : (int)lvl[b][rs - Tt];
            const int le = 1 + (l_lv > r_lv ? l_lv : r_lv);
            lvl[b][nid] = (unsigned char)le;
            node_l[b * NNODE + nid] = ls;
            node_r[b * NNODE + nid] = rs;
            if (le > maxl) maxl = le;
            sp -= 2;
            stck[b][sp] = (short)(Tt + nid); sp += 1;
            nid += 1;
        }
    }
    root_src[b] = (int)stck[b][0];
    for (int i = 0; i < nid; i++) atomicAdd(&counts[lvl[b][i]], 1);
    atomicMax(&maxl_s, maxl);
    __syncthreads();
    if (b == 0) {
        int acc = 0;
        for (int l = 0; l < 256; l++) { offs_s[l] = acc; acc += counts[l]; }
        offs_s[256] = acc;
        max_lv[0] = maxl_s;
    }
    __syncthreads();
    for (int i = b; i < 256; i += Bb) counts[i] = offs_s[i];
    __syncthreads();
    for (int i = 0; i < nid; i++) {
        const int pos = atomicAdd(&counts[lvl[b][i]], 1);
        items[pos] = (b << 16) | i;
    }
    for (int i = b; i < 257; i += Bb) offs[i] = offs_s[i];
}

// ---------------------------------------------------------------------------
// Phase 3: level-synchronous tree evaluation.
// R4 change: child h/c GATHER uses NORMAL CACHED loads (L1/L2). Safety:
//  - dispatch-start acquire invalidates L1/L2 (same mechanism that makes the
//    leaf_kernel -> tree_kernel handoff correct with plain loads);
//  - every node_h/node_c line is sc1-written (-> LLC) pre-barrier, strictly
//    before any read of it post-barrier, so a read-miss pulls the current
//    value from LLC; a reader-cached line is never written again (a line
//    holds columns of exactly one node, written only at that node's level).
// This cuts per-level LLC gather traffic 32x (32 MB -> 1 MB); the 31
// same-XCD re-reads hit L2. Only epilogue stores + barrier slots stay sc1.
// ---------------------------------------------------------------------------
__global__ __launch_bounds__(512) void tree_kernel(
    const float* __restrict__ Wr, const float* __restrict__ br,
    const __hip_bfloat16* __restrict__ leaf_h, const float* __restrict__ leaf_c,
    __hip_bfloat16* __restrict__ node_h, float* __restrict__ node_c,
    const int* __restrict__ node_l, const int* __restrict__ node_r,
    const int* __restrict__ root_src, const int* __restrict__ offs,
    const int* __restrict__ items, const int* __restrict__ max_level,
    float* __restrict__ out, int* __restrict__ slots)
{
    __shared__ __align__(16) __bf16 Wt[16][1032];  // [local col][k], pad +8
    __shared__ float brs[16];
    __shared__ float Cs0[64][17];   // kh=0 partial (left child K-half)
    __shared__ float Cs1[64][17];   // kh=1 partial (right child K-half)
    __shared__ const v8bf* hsl[64];
    __shared__ const v8bf* hsr[64];
    __shared__ const float* csl[64];
    __shared__ const float* csr[64];
    __shared__ int outm[64];

    const int tid = threadIdx.x;
    const int g = blockIdx.x;  // column group: j = 2g, 2g+1

    // Load W_r slice as bf16, transposed. Local col c: gate=c%5, jj=c/5.
    for (int idx = tid; idx < 16 * 1024; idx += 512) {
        const int c = idx >> 10;
        const int k = idx & 1023;
        float v = 0.f;
        if (c < 10) {
            const int col = (c % 5) * Hh + 2 * g + (c / 5);
            v = Wr[(long)k * N5H + col];
        }
        Wt[c][k] = (__bf16)v;
    }
    if (tid < 16) {
        float v = 0.f;
        if (tid < 10) v = br[(tid % 5) * Hh + 2 * g + (tid / 5)];
        brs[tid] = v;
    }
    __syncthreads();

    const int ML = max_level[0];
    const int wave = tid >> 6;
    const int lane = tid & 63;
    const int mt = wave & 3;   // M-tile (16 rows each)
    const int kh = wave >> 2;  // K half (0: left child, 1: right child)
    const int quad = lane >> 4;
    const int l15 = lane & 15;
    const int mrow = mt * 16 + l15;

    const v8bf* leaf_h8 = (const v8bf*)leaf_h;   // 8 bf16 per v8bf
    const v8bf* node_h8 = (const v8bf*)node_h;
    u32* node_h32 = (u32*)node_h;                // 2 bf16 per u32

    // Build the per-chunk pointer/flag tables (barrier-independent metadata).
    auto prep = [&](int base, int M) {
        if (tid < 64) {
            const int m = tid;
            const int it = items[base + (m < M ? m : 0)];
            const int b = it >> 16;
            const int nd = it & 0xffff;
            const int ls = node_l[b * NNODE + nd];
            const int rs = node_r[b * NNODE + nd];
            if (ls < Tt) {
                hsl[m] = leaf_h8 + ((long)b * Tt + ls) * (Hh / 8);
                csl[m] = leaf_c  + ((long)b * Tt + ls) * Hh;
            } else {
                hsl[m] = node_h8 + ((long)b * NNODE + (ls - Tt)) * (Hh / 8);
                csl[m] = node_c  + ((long)b * NNODE + (ls - Tt)) * Hh;
            }
            if (rs < Tt) {
                hsr[m] = leaf_h8 + ((long)b * Tt + rs) * (Hh / 8);
                csr[m] = leaf_c  + ((long)b * Tt + rs) * Hh;
            } else {
                hsr[m] = node_h8 + ((long)b * NNODE + (rs - Tt)) * (Hh / 8);
                csr[m] = node_c  + ((long)b * NNODE + (rs - Tt)) * Hh;
            }
            int fl = it;
            if (Tt + nd == root_src[b]) fl |= (1 << 30);  // root marker
            if (m >= M) fl |= (1 << 29);                  // pad marker
            outm[m] = fl;
        }
    };

    for (int lev = 1; lev <= ML; lev++) {
        const int s = offs[lev], e = offs[lev + 1];
        {
            const int M0 = (e - s < 64) ? (e - s) : 64;
            prep(s, M0);  // metadata loads overlap the barrier wait below
        }
        if (lev > 1 && wave == 0) {
            // Wait for all 256 blocks to finish level lev-1: poll slot array.
            const int need = lev - 1;
            const int* sl = slots + 4 * lane;
            for (;;) {
                const int a0 = __hip_atomic_load(sl + 0, __ATOMIC_RELAXED, __HIP_MEMORY_SCOPE_AGENT);
                const int a1 = __hip_atomic_load(sl + 1, __ATOMIC_RELAXED, __HIP_MEMORY_SCOPE_AGENT);
                const int a2 = __hip_atomic_load(sl + 2, __ATOMIC_RELAXED, __HIP_MEMORY_SCOPE_AGENT);
                const int a3 = __hip_atomic_load(sl + 3, __ATOMIC_RELAXED, __HIP_MEMORY_SCOPE_AGENT);
                const bool ok = (a0 >= need) & (a1 >= need) & (a2 >= need) & (a3 >= need);
                if (__all(ok)) break;
            }
        }
        __syncthreads();

        for (int base = s; base < e; base += 64) {
            const int M = (e - base < 64) ? (e - base) : 64;
            if (base != s) { prep(base, M); __syncthreads(); }

            // Child-c prefetch (cached; overlaps the GEMM latency below).
            float clv0 = 0.f, clv1 = 0.f, crv0 = 0.f, crv1 = 0.f;
            if (tid < 64) {
                const float* clp = csl[tid] + 2 * g;
                const float* crp = csr[tid] + 2 * g;
                clv0 = clp[0]; clv1 = clp[1];
                crv0 = crp[0]; crv1 = crp[1];
            }

            // A gather: this wave's child row (kh picks left/right child),
            // normal cached 16B loads — L2 serves the 32-blocks/XCD reuse.
            const v8bf* hp = kh ? hsr[mrow] : hsl[mrow];
            v8bf a[16];
#pragma unroll
            for (int t = 0; t < 16; t++)
                a[t] = hp[t * 4 + quad];

            v4f acc = {0.f, 0.f, 0.f, 0.f};
#pragma unroll
            for (int t = 0; t < 16; t++) {
                const v8bf wv = *(const v8bf*)&Wt[l15][kh * 512 + t * 32 + quad * 8];
                acc = __builtin_amdgcn_mfma_f32_16x16x32_bf16(a[t], wv, acc, 0, 0, 0);
            }
            {
                float (*Cp)[17] = kh ? Cs1 : Cs0;
#pragma unroll
                for (int rg = 0; rg < 4; rg++) Cp[mt * 16 + quad * 4 + rg][l15] = acc[rg];
            }
            __syncthreads();

            // Epilogue: wave 0 only (keeps all mutable stores in wave 0 so
            // tid 0's s_waitcnt(0) drains them before the slot store).
            if (tid < 64) {
                const int m = tid;
                const int info = outm[m];
                if (!(info & (1 << 29))) {
                    const int b = (info >> 16) & 63;
                    const int nd = info & 0xffff;
                    float hv[2];
                    const float clv[2] = {clv0, clv1};
                    const float crv[2] = {crv0, crv1};
#pragma unroll
                    for (int jj = 0; jj < 2; jj++) {
                        const float iv = Cs0[m][jj * 5 + 0] + Cs1[m][jj * 5 + 0] + brs[jj * 5 + 0];
                        const float fl = Cs0[m][jj * 5 + 1] + Cs1[m][jj * 5 + 1] + brs[jj * 5 + 1];
                        const float fr = Cs0[m][jj * 5 + 2] + Cs1[m][jj * 5 + 2] + brs[jj * 5 + 2];
                        const float gv = Cs0[m][jj * 5 + 3] + Cs1[m][jj * 5 + 3] + brs[jj * 5 + 3];
                        const float ov = Cs0[m][jj * 5 + 4] + Cs1[m][jj * 5 + 4] + brs[jj * 5 + 4];
                        const float c = sigm(iv) * tanhf(gv) + sigm(fl) * clv[jj] + sigm(fr) * crv[jj];
                        hv[jj] = sigm(ov) * tanhf(c);
                        __hip_atomic_store(node_c + ((long)b * NNODE + nd) * Hh + 2 * g + jj, c,
                                           __ATOMIC_RELAXED, __HIP_MEMORY_SCOPE_AGENT);
                    }
                    const __hip_bfloat16 hb0 = __float2bfloat16(hv[0]);
                    const __hip_bfloat16 hb1 = __float2bfloat16(hv[1]);
                    const u32 pack = (u32)(*(const unsigned short*)&hb0)
                                   | ((u32)(*(const unsigned short*)&hb1) << 16);
                    __hip_atomic_store(node_h32 + ((long)b * NNODE + nd) * (Hh / 2) + g, pack,
                                       __ATOMIC_RELAXED, __HIP_MEMORY_SCOPE_AGENT);
                    if (info & (1 << 30)) {
                        out[(long)b * Hh + 2 * g] = hv[0];
                        out[(long)b * Hh + 2 * g + 1] = hv[1];
                    }
                }
            }
        }

        // Arrive: drain wave 0's sc1 stores to the coherence point (LLC),
        // then one plain agent store — no RMW, no same-line serialization.
        if (lev < ML && tid == 0) {
            __builtin_amdgcn_s_waitcnt(0);
            __hip_atomic_store(&slots[blockIdx.x], lev, __ATOMIC_RELAXED, __HIP_MEMORY_SCOPE_AGENT);
        }
    }
}

// ---------------------------------------------------------------------------
extern "C" void kernel_launch(void* const* d_in, const int* in_sizes, int n_in,
                              void* d_out, int out_size, void* d_ws, size_t ws_size,
                              hipStream_t stream)
{
    const float* x   = (const float*)d_in[0];
    const int* trans = (const int*)d_in[1];
    const float* Wx  = (const float*)d_in[2];
    const float* bx  = (const float*)d_in[3];
    const float* Wg  = (const float*)d_in[4];
    const float* bg  = (const float*)d_in[5];
    const float* Wr  = (const float*)d_in[6];
    const float* br  = (const float*)d_in[7];
    float* out = (float*)d_out;

    char* p = (char*)d_ws;
    auto take = [&](size_t bytes) -> char* {
        char* r = p;
        p += (bytes + 255) & ~(size_t)255;
        return r;
    };
    __hip_bfloat16* leaf_h = (__hip_bfloat16*)take((size_t)Bb * Tt * Hh * 2);
    float* leaf_c          = (float*)take((size_t)Bb * Tt * Hh * 4);
    __hip_bfloat16* node_h = (__hip_bfloat16*)take((size_t)Bb * NNODE * Hh * 2);
    float* node_c          = (float*)take((size_t)Bb * NNODE * Hh * 4);
    int* node_l   = (int*)take((size_t)Bb * NNODE * 4);
    int* node_r   = (int*)take((size_t)Bb * NNODE * 4);
    int* root_src = (int*)take(Bb * 4);
    int* offs     = (int*)take(257 * 4);
    int* items    = (int*)take((size_t)Bb * NNODE * 4);
    int* max_lv   = (int*)take(4);
    int* slots    = (int*)take(256 * 4);

    hipLaunchKernelGGL(leaf_kernel, dim3(Hh / 256, (Bb * Tt) / 16), dim3(256), 0, stream,
                       x, Wx, bx, Wg, bg, leaf_h, leaf_c);
    hipLaunchKernelGGL(sched_kernel, dim3(1), dim3(64), 0, stream,
                       trans, node_l, node_r, root_src, offs, items, max_lv, slots);

    void* args[] = { (void*)&Wr, (void*)&br, (void*)&leaf_h, (void*)&leaf_c,
                     (void*)&node_h, (void*)&node_c, (void*)&node_l, (void*)&node_r,
                     (void*)&root_src, (void*)&offs, (void*)&items, (void*)&max_lv,
                     (void*)&out, (void*)&slots };
    hipLaunchCooperativeKernel((const void*)tree_kernel, dim3(256), dim3(512),
                               args, 0, stream);
}